// Round 4
// baseline (98.837 us; speedup 1.0000x reference)
//
#include <hip/hip_runtime.h>
#include <cstdint>

// ---------------------------------------------------------------------------
// QuantumBranch, R4.
// R3 post-mortem: qb_main est. ~26us vs ~12us write roofline; VGPR_Count=36
// vs ~50 live floats in naive phase-1 => spill or strided s_load rework.
// R4: (1) separable phase-1 via m = e01 (x) e23 -> u_i = sum_a e01_a *
//     (sum_b V[i][4a+b] e23_b): 1024 -> ~750 VALU, ~20 live VGPRs.
//     (2) V stored ROW-major -> per-i coefficients are contiguous 64B runs
//     (s_load_dwordx16 friendly).
//     (3) 128-thread blocks (2048 blocks, 8/CU) for phase-diversity overlap.
// Phase 2 (proven R2): LDS-staged q/inv, flat coalesced float4 tile writes.
// ---------------------------------------------------------------------------

#define CONST_AS __attribute__((address_space(4)))
template <typename T>
__device__ inline const CONST_AS T* as_const4(const T* p) {
    return (const CONST_AS T*)(uintptr_t)p;
}

// ws float offsets
#define WS_VRT 0     // 256: Re(V) row-major [i*16+j]
#define WS_VIT 256   // 256: Im(V) row-major
#define WS_A   512   // 256: (W-colmean)*gamma  [k*4+w]
#define WS_B0  768   // 64:  (b-bmean)*gamma
#define WS_G   832   // 16:  G[4][4]
#define WS_g   848   // 4
#define WS_C0  852   // 1

// One wave, no barriers. lane = row*4 + cg; lane holds U[row][4cg..4cg+3].
__global__ __launch_bounds__(64) void qb_setup(const float* __restrict__ wts,
                                               const float* __restrict__ W,
                                               const float* __restrict__ bias,
                                               const float* __restrict__ gamma,
                                               float* __restrict__ ws) {
    const int lane = threadIdx.x;
    const int row  = lane >> 2;
    const int cg   = lane & 3;

    float ur[4], ui[4];   // U[row][4cg+c]
    #pragma unroll
    for (int c = 0; c < 4; ++c) {
        ur[c] = (row == 4*cg + c) ? 1.f : 0.f;
        ui[c] = 0.f;
    }

    #pragma unroll
    for (int l = 0; l < 2; ++l) {
        // Rot on wires 0..3 (wire0 = MSB of row index)
        #pragma unroll
        for (int w = 0; w < 4; ++w) {
            const float ph = wts[l*12 + w*3 + 0];
            const float th = wts[l*12 + w*3 + 1];
            const float om = wts[l*12 + w*3 + 2];
            float st, ct; __sincosf(0.5f*th, &st, &ct);
            float sp, cp; __sincosf(0.5f*(ph+om), &sp, &cp);
            float sm, cm; __sincosf(0.5f*(ph-om), &sm, &cm);
            const float a00r =  cp*ct, a00i = -sp*ct;
            const float a01r = -cm*st, a01i = -sm*st;
            const float a10r =  cm*st, a10i = -sm*st;
            const float a11r =  cp*ct, a11i =  sp*ct;
            const int m = 8 >> w;
            const int xm = m << 2;            // lane xor mask for row^m
            const bool hi = (row & m) != 0;
            #pragma unroll
            for (int c = 0; c < 4; ++c) {
                const float pr = __shfl_xor(ur[c], xm, 64);
                const float pi = __shfl_xor(ui[c], xm, 64);
                float nr, ni;
                if (!hi) {
                    nr = a00r*ur[c] - a00i*ui[c] + a01r*pr - a01i*pi;
                    ni = a00r*ui[c] + a00i*ur[c] + a01r*pi + a01i*pr;
                } else {
                    nr = a11r*ur[c] - a11i*ui[c] + a10r*pr - a10i*pi;
                    ni = a11r*ui[c] + a11i*ur[c] + a10r*pi + a10i*pr;
                }
                ur[c] = nr; ui[c] = ni;
            }
        }
        // CNOT ring, range r = l%3+1: new[row] = old[src(row)]
        const int rr = (l == 0) ? 1 : 2;
        #pragma unroll
        for (int w = 0; w < 4; ++w) {
            const int cmk = 8 >> w;
            const int tmk = 8 >> ((w + rr) & 3);
            const int src = (row & cmk) ? (row ^ tmk) : row;
            const int srcLane = src*4 + cg;
            #pragma unroll
            for (int c = 0; c < 4; ++c) {
                ur[c] = __shfl(ur[c], srcLane, 64);
                ui[c] = __shfl(ui[c], srcLane, 64);
            }
        }
    }

    // V = U * diag((-i)^popc(col)); store ROW-major: ws[. + row*16 + col].
    // Lane's 4 cols are contiguous -> float4 stores.
    {
        float vr4[4], vi4[4];
        #pragma unroll
        for (int c = 0; c < 4; ++c) {
            const int col = 4*cg + c;
            const int p = __popc(col) & 3;
            if (p == 0)      { vr4[c] =  ur[c]; vi4[c] =  ui[c]; }
            else if (p == 1) { vr4[c] =  ui[c]; vi4[c] = -ur[c]; }
            else if (p == 2) { vr4[c] = -ur[c]; vi4[c] = -ui[c]; }
            else             { vr4[c] = -ui[c]; vi4[c] =  ur[c]; }
        }
        *(float4*)(ws + WS_VRT + row*16 + 4*cg) = make_float4(vr4[0], vr4[1], vr4[2], vr4[3]);
        *(float4*)(ws + WS_VIT + row*16 + 4*cg) = make_float4(vi4[0], vi4[1], vi4[2], vi4[3]);
    }

    // Projection / layernorm constants: lane k
    {
        const int k = lane;
        float w0 = W[k*4+0], w1 = W[k*4+1], w2 = W[k*4+2], w3 = W[k*4+3];
        float bk = bias[k];
        auto wsum = [](float v) {
            #pragma unroll
            for (int o = 32; o; o >>= 1) v += __shfl_xor(v, o, 64);
            return v;
        };
        const float inv64 = 1.f/64.f;
        const float m0 = wsum(w0)*inv64, m1 = wsum(w1)*inv64;
        const float m2 = wsum(w2)*inv64, m3 = wsum(w3)*inv64;
        const float bm = wsum(bk)*inv64;
        float cc[4] = {w0-m0, w1-m1, w2-m2, w3-m3};
        const float bc = bk - bm;
        const float gk = gamma[k];
        #pragma unroll
        for (int w = 0; w < 4; ++w) ws[WS_A + k*4 + w] = cc[w]*gk;
        ws[WS_B0 + k] = bc*gk;
        #pragma unroll
        for (int a = 0; a < 4; ++a)
            #pragma unroll
            for (int b2 = 0; b2 < 4; ++b2) {
                const float s = wsum(cc[a]*cc[b2])*inv64;
                if (k == 0) ws[WS_G + a*4 + b2] = s;
            }
        #pragma unroll
        for (int a = 0; a < 4; ++a) {
            const float s = wsum(bc*cc[a])*inv64;
            if (k == 0) ws[WS_g + a] = s;
        }
        {
            const float s = wsum(bc*bc)*inv64;
            if (k == 0) ws[WS_C0] = s;
        }
    }
}

#define BLK 128

__global__ __launch_bounds__(BLK) void qb_main(const float* __restrict__ x,
                                               const float* __restrict__ beta,
                                               const float* __restrict__ ws_g,
                                               float* __restrict__ out) {
    __shared__ float4 lq[BLK];
    __shared__ float  linv[BLK];

    const int tid = threadIdx.x;
    const int sample = blockIdx.x * BLK + tid;
    const float4 xv = ((const float4*)x)[sample];

    // phase 2 coefficient preload (iter-invariant column tid&15)
    const int k4t = tid & 15;
    float4 A4[4]; float B04[4], Bt4[4];
    #pragma unroll
    for (int u = 0; u < 4; ++u) {
        const int k = k4t*4 + u;
        A4[u]  = ((const float4*)(ws_g + WS_A))[k];
        B04[u] = ws_g[WS_B0 + k];
        Bt4[u] = beta[k];
    }

    // --- phase 1: embedding products ---
    float c[4], s[4];
    {
        const float xa[4] = {xv.x, xv.y, xv.z, xv.w};
        #pragma unroll
        for (int w = 0; w < 4; ++w) {
            const float h = tanhf(xa[w]) * 1.5707963267948966f;
            __sincosf(h, &s[w], &c[w]);
        }
    }
    const float e01[4] = {c[0]*c[1], c[0]*s[1], s[0]*c[1], s[0]*s[1]};
    const float e23[4] = {c[2]*c[3], c[2]*s[3], s[2]*c[3], s[2]*s[3]};

    // separable matvec: u_i = sum_a e01[a] * (sum_b V[i][4a+b] * e23[b])
    const CONST_AS float* V = as_const4(ws_g);
    float z0 = 0.f, z1 = 0.f, z2 = 0.f, z3 = 0.f;
    #pragma unroll
    for (int i = 0; i < 16; ++i) {
        float ur = 0.f, ui = 0.f;
        #pragma unroll
        for (int a = 0; a < 4; ++a) {
            float tr = 0.f, ti = 0.f;
            #pragma unroll
            for (int b = 0; b < 4; ++b) {
                tr = fmaf(V[WS_VRT + i*16 + 4*a + b], e23[b], tr);
                ti = fmaf(V[WS_VIT + i*16 + 4*a + b], e23[b], ti);
            }
            ur = fmaf(e01[a], tr, ur);
            ui = fmaf(e01[a], ti, ui);
        }
        const float p = fmaf(ur, ur, ui*ui);
        z0 += (i & 8) ? -p : p;
        z1 += (i & 4) ? -p : p;
        z2 += (i & 2) ? -p : p;
        z3 += (i & 1) ? -p : p;
    }

    const float mx = fmaxf(fmaxf(z0, z1), fmaxf(z2, z3));
    const float e0 = __expf(z0-mx), e1 = __expf(z1-mx);
    const float e2 = __expf(z2-mx), e3 = __expf(z3-mx);
    const float rs = 1.f / (e0+e1+e2+e3);
    const float4 qv = make_float4(e0*rs, e1*rs, e2*rs, e3*rs);

    float var = V[WS_C0];
    {
        const float qa[4] = {qv.x, qv.y, qv.z, qv.w};
        #pragma unroll
        for (int a = 0; a < 4; ++a) {
            float t = 2.f * V[WS_g + a];
            #pragma unroll
            for (int b2 = 0; b2 < 4; ++b2) t = fmaf(V[WS_G + a*4 + b2], qa[b2], t);
            var = fmaf(qa[a], t, var);
        }
    }
    const float inv = rsqrtf(var + 1e-5f);

    lq[tid]   = qv;
    linv[tid] = inv;
    __syncthreads();

    // --- phase 2: coalesced tile write (block tile = BLK samples x 16 float4) ---
    float4* outv = (float4*)out + (size_t)blockIdx.x * (BLK * 16);
    #pragma unroll
    for (int iter = 0; iter < 16; ++iter) {
        const int f  = iter*BLK + tid;
        const int sl = f >> 4;               // 16 lanes share one sample
        const float4 q  = lq[sl];
        const float  iv = linv[sl];
        float4 o;
        float* op = (float*)&o;
        #pragma unroll
        for (int u = 0; u < 4; ++u) {
            float t = B04[u];
            t = fmaf(A4[u].x, q.x, t);
            t = fmaf(A4[u].y, q.y, t);
            t = fmaf(A4[u].z, q.z, t);
            t = fmaf(A4[u].w, q.w, t);
            op[u] = fmaf(t, iv, Bt4[u]);
        }
        outv[f] = o;
    }
}

extern "C" void kernel_launch(void* const* d_in, const int* in_sizes, int n_in,
                              void* d_out, int out_size, void* d_ws, size_t ws_size,
                              hipStream_t stream) {
    const float* x     = (const float*)d_in[0];
    const float* wts   = (const float*)d_in[1];
    const float* W     = (const float*)d_in[2];
    const float* bias  = (const float*)d_in[3];
    const float* gamma = (const float*)d_in[4];
    const float* beta  = (const float*)d_in[5];
    float* out = (float*)d_out;
    float* ws  = (float*)d_ws;
    const int B = in_sizes[0] / 4;   // 262144

    hipLaunchKernelGGL(qb_setup, dim3(1), dim3(64), 0, stream, wts, W, bias, gamma, ws);
    hipLaunchKernelGGL(qb_main, dim3(B / BLK), dim3(BLK), 0, stream, x, beta, ws, out);
}

// Round 5
// 97.776 us; speedup vs baseline: 1.0108x; 1.0108x over previous
//
#include <hip/hip_runtime.h>
#include <cstdint>

// ---------------------------------------------------------------------------
// QuantumBranch, R5.
// R4 post-mortem: three neutral rounds; qb_main est ~26us vs ~12us write
// roofline, insensitive to compute cuts / block size / V layout. Remaining
// suspect: per-iter ds_read -> VALU -> store chain throttles store ISSUE
// (~2 iters in flight at VGPR~40, each store eats ~120cy LDS latency).
// R5: phase 2 preloads (q,inv) for 8 iters into registers in one LDS burst,
// then fires 8 stores back-to-back (2 groups). 256-thr blocks (4 waves).
// tanhf -> 1 - 2/(exp(2x)+1) via __expf + fast divide (no libm branches).
//
// Math (verified R1-R4): circuit collapses to V = U*diag((-i)^popc);
// z_w = sum_i +/-(r_i^2+s_i^2), r+is = V m, m = e01 (x) e23 from
// tanh(x)*pi/2 half-angles. LayerNorm collapses to 4x4 quadratic form.
// out[b,k] = inv_b*(A[k].q_b + B0[k]) + beta[k].
// ---------------------------------------------------------------------------

#define CONST_AS __attribute__((address_space(4)))
template <typename T>
__device__ inline const CONST_AS T* as_const4(const T* p) {
    return (const CONST_AS T*)(uintptr_t)p;
}

// ws float offsets
#define WS_VRT 0     // 256: Re(V) row-major [i*16+j]
#define WS_VIT 256   // 256: Im(V) row-major
#define WS_A   512   // 256: (W-colmean)*gamma  [k*4+w]
#define WS_B0  768   // 64:  (b-bmean)*gamma
#define WS_G   832   // 16:  G[4][4]
#define WS_g   848   // 4
#define WS_C0  852   // 1

// One wave, no barriers. lane = row*4 + cg; lane holds U[row][4cg..4cg+3].
__global__ __launch_bounds__(64) void qb_setup(const float* __restrict__ wts,
                                               const float* __restrict__ W,
                                               const float* __restrict__ bias,
                                               const float* __restrict__ gamma,
                                               float* __restrict__ ws) {
    const int lane = threadIdx.x;
    const int row  = lane >> 2;
    const int cg   = lane & 3;

    float ur[4], ui[4];   // U[row][4cg+c]
    #pragma unroll
    for (int c = 0; c < 4; ++c) {
        ur[c] = (row == 4*cg + c) ? 1.f : 0.f;
        ui[c] = 0.f;
    }

    #pragma unroll
    for (int l = 0; l < 2; ++l) {
        // Rot on wires 0..3 (wire0 = MSB of row index)
        #pragma unroll
        for (int w = 0; w < 4; ++w) {
            const float ph = wts[l*12 + w*3 + 0];
            const float th = wts[l*12 + w*3 + 1];
            const float om = wts[l*12 + w*3 + 2];
            float st, ct; __sincosf(0.5f*th, &st, &ct);
            float sp, cp; __sincosf(0.5f*(ph+om), &sp, &cp);
            float sm, cm; __sincosf(0.5f*(ph-om), &sm, &cm);
            const float a00r =  cp*ct, a00i = -sp*ct;
            const float a01r = -cm*st, a01i = -sm*st;
            const float a10r =  cm*st, a10i = -sm*st;
            const float a11r =  cp*ct, a11i =  sp*ct;
            const int m = 8 >> w;
            const int xm = m << 2;            // lane xor mask for row^m
            const bool hi = (row & m) != 0;
            #pragma unroll
            for (int c = 0; c < 4; ++c) {
                const float pr = __shfl_xor(ur[c], xm, 64);
                const float pi = __shfl_xor(ui[c], xm, 64);
                float nr, ni;
                if (!hi) {
                    nr = a00r*ur[c] - a00i*ui[c] + a01r*pr - a01i*pi;
                    ni = a00r*ui[c] + a00i*ur[c] + a01r*pi + a01i*pr;
                } else {
                    nr = a11r*ur[c] - a11i*ui[c] + a10r*pr - a10i*pi;
                    ni = a11r*ui[c] + a11i*ur[c] + a10r*pi + a10i*pr;
                }
                ur[c] = nr; ui[c] = ni;
            }
        }
        // CNOT ring, range r = l%3+1: new[row] = old[src(row)]
        const int rr = (l == 0) ? 1 : 2;
        #pragma unroll
        for (int w = 0; w < 4; ++w) {
            const int cmk = 8 >> w;
            const int tmk = 8 >> ((w + rr) & 3);
            const int src = (row & cmk) ? (row ^ tmk) : row;
            const int srcLane = src*4 + cg;
            #pragma unroll
            for (int c = 0; c < 4; ++c) {
                ur[c] = __shfl(ur[c], srcLane, 64);
                ui[c] = __shfl(ui[c], srcLane, 64);
            }
        }
    }

    // V = U * diag((-i)^popc(col)); store ROW-major: ws[. + row*16 + col].
    {
        float vr4[4], vi4[4];
        #pragma unroll
        for (int c = 0; c < 4; ++c) {
            const int col = 4*cg + c;
            const int p = __popc(col) & 3;
            if (p == 0)      { vr4[c] =  ur[c]; vi4[c] =  ui[c]; }
            else if (p == 1) { vr4[c] =  ui[c]; vi4[c] = -ur[c]; }
            else if (p == 2) { vr4[c] = -ur[c]; vi4[c] = -ui[c]; }
            else             { vr4[c] = -ui[c]; vi4[c] =  ur[c]; }
        }
        *(float4*)(ws + WS_VRT + row*16 + 4*cg) = make_float4(vr4[0], vr4[1], vr4[2], vr4[3]);
        *(float4*)(ws + WS_VIT + row*16 + 4*cg) = make_float4(vi4[0], vi4[1], vi4[2], vi4[3]);
    }

    // Projection / layernorm constants: lane k
    {
        const int k = lane;
        float w0 = W[k*4+0], w1 = W[k*4+1], w2 = W[k*4+2], w3 = W[k*4+3];
        float bk = bias[k];
        auto wsum = [](float v) {
            #pragma unroll
            for (int o = 32; o; o >>= 1) v += __shfl_xor(v, o, 64);
            return v;
        };
        const float inv64 = 1.f/64.f;
        const float m0 = wsum(w0)*inv64, m1 = wsum(w1)*inv64;
        const float m2 = wsum(w2)*inv64, m3 = wsum(w3)*inv64;
        const float bm = wsum(bk)*inv64;
        float cc[4] = {w0-m0, w1-m1, w2-m2, w3-m3};
        const float bc = bk - bm;
        const float gk = gamma[k];
        #pragma unroll
        for (int w = 0; w < 4; ++w) ws[WS_A + k*4 + w] = cc[w]*gk;
        ws[WS_B0 + k] = bc*gk;
        #pragma unroll
        for (int a = 0; a < 4; ++a)
            #pragma unroll
            for (int b2 = 0; b2 < 4; ++b2) {
                const float s = wsum(cc[a]*cc[b2])*inv64;
                if (k == 0) ws[WS_G + a*4 + b2] = s;
            }
        #pragma unroll
        for (int a = 0; a < 4; ++a) {
            const float s = wsum(bc*cc[a])*inv64;
            if (k == 0) ws[WS_g + a] = s;
        }
        {
            const float s = wsum(bc*bc)*inv64;
            if (k == 0) ws[WS_C0] = s;
        }
    }
}

#define BLK 256

__global__ __launch_bounds__(BLK) void qb_main(const float* __restrict__ x,
                                               const float* __restrict__ beta,
                                               const float* __restrict__ ws_g,
                                               float* __restrict__ out) {
    __shared__ float4 lq[BLK];
    __shared__ float  linv[BLK];

    const int tid = threadIdx.x;
    const int sample = blockIdx.x * BLK + tid;
    const float4 xv = ((const float4*)x)[sample];

    // phase 2 coefficient preload (iter-invariant column tid&15)
    const int k4t = tid & 15;
    float4 A4[4]; float B04[4], Bt4[4];
    #pragma unroll
    for (int u = 0; u < 4; ++u) {
        const int k = k4t*4 + u;
        A4[u]  = ((const float4*)(ws_g + WS_A))[k];
        B04[u] = ws_g[WS_B0 + k];
        Bt4[u] = beta[k];
    }

    // --- phase 1: embedding products (fast tanh: 1 - 2/(e^{2x}+1)) ---
    float c[4], s[4];
    {
        const float xa[4] = {xv.x, xv.y, xv.z, xv.w};
        #pragma unroll
        for (int w = 0; w < 4; ++w) {
            const float e2 = __expf(xa[w] * 2.885390081777927f);  // 2x * log2e folded by compiler
            const float th = 1.f - __fdividef(2.f, __expf(2.f * xa[w]) + 1.f);
            (void)e2;
            const float h = th * 1.5707963267948966f;
            __sincosf(h, &s[w], &c[w]);
        }
    }
    const float e01[4] = {c[0]*c[1], c[0]*s[1], s[0]*c[1], s[0]*s[1]};
    const float e23[4] = {c[2]*c[3], c[2]*s[3], s[2]*c[3], s[2]*s[3]};

    // separable matvec: u_i = sum_a e01[a] * (sum_b V[i][4a+b] * e23[b])
    const CONST_AS float* V = as_const4(ws_g);
    float z0 = 0.f, z1 = 0.f, z2 = 0.f, z3 = 0.f;
    #pragma unroll
    for (int i = 0; i < 16; ++i) {
        float ur = 0.f, ui = 0.f;
        #pragma unroll
        for (int a = 0; a < 4; ++a) {
            float tr = 0.f, ti = 0.f;
            #pragma unroll
            for (int b = 0; b < 4; ++b) {
                tr = fmaf(V[WS_VRT + i*16 + 4*a + b], e23[b], tr);
                ti = fmaf(V[WS_VIT + i*16 + 4*a + b], e23[b], ti);
            }
            ur = fmaf(e01[a], tr, ur);
            ui = fmaf(e01[a], ti, ui);
        }
        const float p = fmaf(ur, ur, ui*ui);
        z0 += (i & 8) ? -p : p;
        z1 += (i & 4) ? -p : p;
        z2 += (i & 2) ? -p : p;
        z3 += (i & 1) ? -p : p;
    }

    const float mx = fmaxf(fmaxf(z0, z1), fmaxf(z2, z3));
    const float e0 = __expf(z0-mx), e1 = __expf(z1-mx);
    const float e2 = __expf(z2-mx), e3 = __expf(z3-mx);
    const float rs = 1.f / (e0+e1+e2+e3);
    const float4 qv = make_float4(e0*rs, e1*rs, e2*rs, e3*rs);

    float var = V[WS_C0];
    {
        const float qa[4] = {qv.x, qv.y, qv.z, qv.w};
        #pragma unroll
        for (int a = 0; a < 4; ++a) {
            float t = 2.f * V[WS_g + a];
            #pragma unroll
            for (int b2 = 0; b2 < 4; ++b2) t = fmaf(V[WS_G + a*4 + b2], qa[b2], t);
            var = fmaf(qa[a], t, var);
        }
    }
    const float inv = rsqrtf(var + 1e-5f);

    lq[tid]   = qv;
    linv[tid] = inv;
    __syncthreads();

    // --- phase 2: coalesced tile write. Preload 8 iterations' (q,inv) into
    // registers in one LDS burst, then fire 8 back-to-back stores. ---
    float4* outv = (float4*)out + (size_t)blockIdx.x * (BLK * 16);
    const int sl0 = tid >> 4;                // 16 lanes share one sample
    #pragma unroll
    for (int g = 0; g < 2; ++g) {
        float4 q8[8]; float iv8[8];
        #pragma unroll
        for (int j = 0; j < 8; ++j) {
            const int sl = (g*8 + j)*16 + sl0;
            q8[j]  = lq[sl];
            iv8[j] = linv[sl];
        }
        #pragma unroll
        for (int j = 0; j < 8; ++j) {
            const int f = (g*8 + j)*BLK + tid;
            float4 o;
            float* op = (float*)&o;
            #pragma unroll
            for (int u = 0; u < 4; ++u) {
                float t = B04[u];
                t = fmaf(A4[u].x, q8[j].x, t);
                t = fmaf(A4[u].y, q8[j].y, t);
                t = fmaf(A4[u].z, q8[j].z, t);
                t = fmaf(A4[u].w, q8[j].w, t);
                op[u] = fmaf(t, iv8[j], Bt4[u]);
            }
            outv[f] = o;
        }
    }
}

extern "C" void kernel_launch(void* const* d_in, const int* in_sizes, int n_in,
                              void* d_out, int out_size, void* d_ws, size_t ws_size,
                              hipStream_t stream) {
    const float* x     = (const float*)d_in[0];
    const float* wts   = (const float*)d_in[1];
    const float* W     = (const float*)d_in[2];
    const float* bias  = (const float*)d_in[3];
    const float* gamma = (const float*)d_in[4];
    const float* beta  = (const float*)d_in[5];
    float* out = (float*)d_out;
    float* ws  = (float*)d_ws;
    const int B = in_sizes[0] / 4;   // 262144

    hipLaunchKernelGGL(qb_setup, dim3(1), dim3(64), 0, stream, wts, W, bias, gamma, ws);
    hipLaunchKernelGGL(qb_main, dim3(B / BLK), dim3(BLK), 0, stream, x, beta, ws, out);
}